// Round 3
// baseline (213.763 us; speedup 1.0000x reference)
//
#include <hip/hip_runtime.h>

#define N_NODES 100000
#define N_EDGES 1200000
#define NF 64

typedef __attribute__((ext_vector_type(8))) short short8;
typedef __attribute__((ext_vector_type(4))) float float4v;

__device__ __forceinline__ ushort f2bf(float f) {
    unsigned u = __float_as_uint(f);
    return (ushort)((u + 0x7FFF + ((u >> 16) & 1)) >> 16);  // RNE
}

// binning: bin = node >> 8, 391 bins of 256 nodes
#define NBINS 391
#define CAP 4352                 // in-edges ~3072+3.3sigma + pads<=768 + 16 tail << 4352
#define EPB 2048                 // edges per sort block (8/thread, in registers)
#define NBLK 586                 // ceil(1200000/2048)
#define NI4 (N_EDGES / 4)        // 300000 int4s per row/col array

// ---------------- workspace layout (bytes), flat (~44 MB of 268 MB)
#define OFF_CNT    0             // int[100000]
#define OFF_ENDP   400128        // int[100000]
#define OFF_DINV   800256        // float[100000]
#define OFF_CUR    1200384       // int[2*391] bin-relative cursors (memset 0)
#define OFF_PKW    1203584       // ushort[2*1024*8] = 32 KB packed B-fragments
#define OFF_SRCS   1236352       // int[391*4352]    = 6.8 MB (final, dst-binned)
#define OFF_SBIN   8042880       // ushort[391*4352] = 3.4 MB staging
#define OFF_DBIN   11446144      // int[391*4352]    = 6.8 MB staging
#define OFF_EMBBF  18252672      // ushort[6.4M] = 12.8 MB
#define OFF_HBF    31052672      // ushort[6.4M] = 12.8 MB -> ends 43,852,672

// Fused: blocks [0,586) binsort (long pole, dispatched first);
//        blocks [586,594) W-pack; blocks [594, 594+3125) emb f32->bf16.
// cur[] is BIN-RELATIVE (zeroed by hipMemsetAsync before this launch).
// Sort blocks keep their 8 edges in REGISTERS (no LDS edge cache).
__global__ __launch_bounds__(256) void prepsort(const float* __restrict__ W10,
                                                const float* __restrict__ W11,
                                                const float* __restrict__ W20,
                                                const float* __restrict__ W21,
                                                ushort* __restrict__ pk,
                                                const float* __restrict__ emb,
                                                ushort* __restrict__ emb_bf,
                                                const int* __restrict__ row,
                                                const int* __restrict__ col,
                                                int* __restrict__ cur,
                                                ushort* __restrict__ sbinned,
                                                int* __restrict__ dbinned) {
    int b = blockIdx.x;
    int t = threadIdx.x;
    if (b < NBLK) {
        __shared__ int sh[NBINS], dh[NBINS];
        __shared__ int sbase[NBINS], dbase[NBINS];   // 6.3 KB total
        for (int i = t; i < NBINS; i += 256) { sh[i] = 0; dh[i] = 0; }
        __syncthreads();
        // 8 edges per thread, held in registers
        int i40 = (b * (EPB / 4)) + t * 2;
        int4 r0 = make_int4(-1, -1, -1, -1), c0 = r0, r1 = r0, c1 = r0;
        if (i40 < NI4)     { r0 = ((const int4*)row)[i40];     c0 = ((const int4*)col)[i40]; }
        if (i40 + 1 < NI4) { r1 = ((const int4*)row)[i40 + 1]; c1 = ((const int4*)col)[i40 + 1]; }
        int s_[8] = {r0.x, r0.y, r0.z, r0.w, r1.x, r1.y, r1.z, r1.w};
        int d_[8] = {c0.x, c0.y, c0.z, c0.w, c1.x, c1.y, c1.z, c1.w};
#pragma unroll
        for (int j = 0; j < 8; ++j)
            if (s_[j] >= 0 && s_[j] != d_[j]) {
                atomicAdd(&sh[s_[j] >> 8], 1);
                atomicAdd(&dh[d_[j] >> 8], 1);
            }
        __syncthreads();
        for (int i = t; i < NBINS; i += 256) {
            if (sh[i]) sbase[i] = i * CAP + atomicAdd(&cur[i], sh[i]);
            if (dh[i]) dbase[i] = i * CAP + atomicAdd(&cur[NBINS + i], dh[i]);
        }
        __syncthreads();
#pragma unroll
        for (int j = 0; j < 8; ++j) {
            int s = s_[j], d = d_[j];
            if (s >= 0 && s != d) {
                int ss = atomicAdd(&sbase[s >> 8], 1);
                sbinned[ss] = (ushort)(s & 255);
                int ds = atomicAdd(&dbase[d >> 8], 1);
                dbinned[ds] = (s << 8) | (d & 255);
            }
        }
    } else if (b < NBLK + 8) {
        int idx = (b - NBLK) * 256 + t;   // [0, 2048)
        int layer = idx >> 10;
        int rest = idx & 1023;
        int f = rest >> 6, L = rest & 63;
        int n = (f & 3) * 16 + (L & 15);
        int kb = (f >> 2) * 32 + ((L >> 4) << 3);
#pragma unroll
        for (int j = 0; j < 8; ++j) {
            int k = kb + j;
            const float* W = layer ? ((k < 64) ? W20 : W21) : ((k < 64) ? W10 : W11);
            pk[idx * 8 + j] = f2bf(W[(k & 63) * 64 + n]);
        }
    } else {
        int bb = b - NBLK - 8;            // [0, 3125)
        int i = (bb * 256 + t) * 8;
        float4 v0 = *(const float4*)(emb + i);
        float4 v1 = *(const float4*)(emb + i + 4);
        uint4 o;
        o.x = (uint)f2bf(v0.x) | ((uint)f2bf(v0.y) << 16);
        o.y = (uint)f2bf(v0.z) | ((uint)f2bf(v0.w) << 16);
        o.z = (uint)f2bf(v1.x) | ((uint)f2bf(v1.y) << 16);
        o.w = (uint)f2bf(v1.z) | ((uint)f2bf(v1.w) << 16);
        *(uint4*)(emb_bf + i) = o;
    }
}

// blocks [0,391): per src-bin hist -> dinv (out-degree, matches reference)
// blocks [391,782): per dst-bin single-pass (LDS cache) hist+scan+scatter
__global__ __launch_bounds__(256) void build(const ushort* __restrict__ sbinned,
                                             const int* __restrict__ dbinned,
                                             const int* __restrict__ cur,
                                             float* __restrict__ dinv,
                                             int* __restrict__ cnt,
                                             int* __restrict__ endp,
                                             int* __restrict__ srcs) {
    int t = threadIdx.x;
    int b = blockIdx.x;
    if (b < NBINS) {
        __shared__ int hist[256];
        hist[t] = 0;
        __syncthreads();
        int start = b * CAP;
        int end = start + cur[b];
        for (int i = start + t; i < end; i += 256)
            atomicAdd(&hist[sbinned[i]], 1);
        __syncthreads();
        int n0 = (b << 8) + t;
        if (n0 < N_NODES) dinv[n0] = hist[t] ? rsqrtf((float)hist[t]) : 0.0f;
    } else {
        int bb = b - NBINS;
        __shared__ int ecache[CAP];           // 17.4 KB: whole bin cached once
        __shared__ int hist[256];
        __shared__ int lcur[256];
        __shared__ int tot_s;
        hist[t] = 0;
        __syncthreads();
        int start = bb * CAP;
        int len = cur[NBINS + bb];
        for (int i = t; i < len; i += 256) {
            int p = dbinned[start + i];
            ecache[i] = p;
            atomicAdd(&hist[p & 255], 1);
        }
        __syncthreads();
        int o0 = hist[t];
        int A0 = (o0 + 3) & ~3;
        __syncthreads();
        hist[t] = A0;
        __syncthreads();
        for (int off = 1; off < 256; off <<= 1) {
            int v = (t >= off) ? hist[t - off] : 0;
            __syncthreads();
            hist[t] += v;
            __syncthreads();
        }
        int e0 = hist[t] - A0;   // exclusive (aligned)
        if (t == 255) tot_s = hist[255];
        lcur[t] = start + e0;
        int n0 = (bb << 8) + t;
        if (n0 < N_NODES) { cnt[n0] = o0; endp[n0] = start + e0 + o0; }
        __syncthreads();
        for (int i = t; i < len; i += 256) {
            int p = ecache[i];
            int slot = atomicAdd(&lcur[p & 255], 1);
            srcs[slot] = p >> 8;
        }
        __syncthreads();
        // zero-fill per-node alignment pads (address-safety for int4 overreads)
        for (int k = o0; k < A0; ++k) srcs[start + e0 + k] = 0;
        // zero-fill 16-slot bin tail (layer's straight-line 2x8 chunks may overread)
        if (t < 16) srcs[start + tot_s + t] = 0;
    }
}

// Fused layer (UNCHANGED from round 2): 16 nodes/wave; 4 edges/gather-instr;
// pair-interleaved chunks; dinv[src] on the fly; -dinv[dst] applied once/node.
#define NPW 16
#define WPB 2
#define NPB (NPW * WPB)                       // 32
#define LB2 ((N_NODES + NPB - 1) / NPB)       // 3125

__global__ __launch_bounds__(128, 8) void cheb_layer(const ushort* __restrict__ x,
                                                     const int* __restrict__ srcs,
                                                     const float* __restrict__ dinv,
                                                     const int* __restrict__ endp,
                                                     const int* __restrict__ cnt,
                                                     const ushort* __restrict__ pk,
                                                     const float* __restrict__ bias,
                                                     ushort* __restrict__ out_bf,
                                                     float* __restrict__ out_f32,
                                                     int last) {
    __shared__ ushort sA[WPB][16][136];   // 8.7 KB

    int t = threadIdx.x;
    int lane = t & 63, wid = t >> 6;
    int c = lane & 15, q = lane >> 4;
    int qd = q, fg = c;
    int nb = blockIdx.x * NPB + wid * NPW;

    int nend = 0, ncnt = 0;
    if (lane < NPW && nb + lane < N_NODES) {
        nend = endp[nb + lane];
        ncnt = cnt[nb + lane];
    }

    const uint2* xr = (const uint2*)x;   // row = 16 uint2 (64 bf16)

    auto chunk8 = [&](int eb, int eendL, float& a0, float& a1, float& a2, float& a3) {
        int4 sv = *(const int4*)(srcs + eb);       // edges eb..eb+3 (uniform)
        int4 sw = *(const int4*)(srcs + eb + 4);   // edges eb+4..eb+7
        int sA01 = (qd & 1) ? sv.y : sv.x;
        int sA23 = (qd & 1) ? sv.w : sv.z;
        int srcA = (qd & 2) ? sA23 : sA01;
        int sB01 = (qd & 1) ? sw.y : sw.x;
        int sB23 = (qd & 1) ? sw.w : sw.z;
        int srcB = (qd & 2) ? sB23 : sB01;
        float nAf = dinv[srcA];                    // broadcast within quarter
        float nBf = dinv[srcB];
        nAf = (eb + qd < eendL) ? nAf : 0.0f;
        nBf = (eb + 4 + qd < eendL) ? nBf : 0.0f;
        uint2 gA = xr[(size_t)srcA * 16 + fg];
        uint2 gB = xr[(size_t)srcB * 16 + fg];
        a0 = fmaf(nAf, __uint_as_float(gA.x << 16), a0);
        a1 = fmaf(nAf, __uint_as_float(gA.x & 0xffff0000u), a1);
        a2 = fmaf(nAf, __uint_as_float(gA.y << 16), a2);
        a3 = fmaf(nAf, __uint_as_float(gA.y & 0xffff0000u), a3);
        a0 = fmaf(nBf, __uint_as_float(gB.x << 16), a0);
        a1 = fmaf(nBf, __uint_as_float(gB.x & 0xffff0000u), a1);
        a2 = fmaf(nBf, __uint_as_float(gB.y << 16), a2);
        a3 = fmaf(nBf, __uint_as_float(gB.y & 0xffff0000u), a3);
    };

#pragma unroll
    for (int gp = 0; gp < NPW; gp += 2) {
        int cn0 = __builtin_amdgcn_readlane(ncnt, gp);
        int ee0 = __builtin_amdgcn_readlane(nend, gp);
        int cn1 = __builtin_amdgcn_readlane(ncnt, gp + 1);
        int ee1 = __builtin_amdgcn_readlane(nend, gp + 1);
        int s0 = ee0 - cn0, s1 = ee1 - cn1;   // 4-aligned starts
        float a0 = 0, a1 = 0, a2 = 0, a3 = 0;
        float b0 = 0, b1 = 0, b2 = 0, b3 = 0;

        // static 2x8-edge chunks per node, pair-interleaved (masked; safe via tail)
        chunk8(s0,     ee0, a0, a1, a2, a3);
        chunk8(s1,     ee1, b0, b1, b2, b3);
        chunk8(s0 + 8, ee0, a0, a1, a2, a3);
        chunk8(s1 + 8, ee1, b0, b1, b2, b3);
        // rare heavy nodes (cn > 16)
        for (int e = s0 + 16; e < ee0; e += 8) chunk8(e, ee0, a0, a1, a2, a3);
        for (int e = s1 + 16; e < ee1; e += 8) chunk8(e, ee1, b0, b1, b2, b3);

        // interleaved cross-quarter reductions for both nodes
        a0 += __shfl_xor(a0, 16, 64); b0 += __shfl_xor(b0, 16, 64);
        a1 += __shfl_xor(a1, 16, 64); b1 += __shfl_xor(b1, 16, 64);
        a2 += __shfl_xor(a2, 16, 64); b2 += __shfl_xor(b2, 16, 64);
        a3 += __shfl_xor(a3, 16, 64); b3 += __shfl_xor(b3, 16, 64);
        a0 += __shfl_xor(a0, 32, 64); b0 += __shfl_xor(b0, 32, 64);
        a1 += __shfl_xor(a1, 32, 64); b1 += __shfl_xor(b1, 32, 64);
        a2 += __shfl_xor(a2, 32, 64); b2 += __shfl_xor(b2, 32, 64);
        a3 += __shfl_xor(a3, 32, 64); b3 += __shfl_xor(b3, 32, 64);

        int node0 = nb + gp, node1 = nb + gp + 1;
        int ni0 = (node0 < N_NODES) ? node0 : 0;
        int ni1 = (node1 < N_NODES) ? node1 : 0;
        if (qd == 0) {
            uint2 xv0 = xr[(size_t)ni0 * 16 + fg];
            uint2 xv1 = xr[(size_t)ni1 * 16 + fg];
            *(uint2*)&sA[wid][gp][4 * fg] = xv0;
            *(uint2*)&sA[wid][gp + 1][4 * fg] = xv1;
        }
        if (qd == 1) {
            float sc0 = -dinv[ni0];   // apply dst-side norm once per node
            float sc1 = -dinv[ni1];
            uint2 p0, p1;
            p0.x = (uint)f2bf(a0 * sc0) | ((uint)f2bf(a1 * sc0) << 16);
            p0.y = (uint)f2bf(a2 * sc0) | ((uint)f2bf(a3 * sc0) << 16);
            p1.x = (uint)f2bf(b0 * sc1) | ((uint)f2bf(b1 * sc1) << 16);
            p1.y = (uint)f2bf(b2 * sc1) | ((uint)f2bf(b3 * sc1) << 16);
            *(uint2*)&sA[wid][gp][64 + 4 * fg] = p0;
            *(uint2*)&sA[wid][gp + 1][64 + 4 * fg] = p1;
        }
    }
    __builtin_amdgcn_wave_barrier();

    const short8* pk8 = (const short8*)pk;
    float4v C[4];
#pragma unroll
    for (int nt = 0; nt < 4; ++nt) {
        float b = bias[nt * 16 + c];
        C[nt] = (float4v){b, b, b, b};
    }
#pragma unroll
    for (int kt = 0; kt < 4; ++kt) {
        short8 af = *(const short8*)&sA[wid][c][kt * 32 + q * 8];
#pragma unroll
        for (int nt = 0; nt < 4; ++nt) {
            short8 bfr = pk8[(kt * 4 + nt) * 64 + lane];
            C[nt] = __builtin_amdgcn_mfma_f32_16x16x32_bf16(af, bfr, C[nt], 0, 0, 0);
        }
    }

#pragma unroll
    for (int nt = 0; nt < 4; ++nt) {
#pragma unroll
        for (int i = 0; i < 4; ++i) {
            int node = nb + q * 4 + i;
            if (node < N_NODES) {
                float v = C[nt][i];
                if (!last) {
                    v = fmaxf(v, 0.0f);
                    out_bf[(size_t)node * NF + nt * 16 + c] = f2bf(v);
                } else {
                    out_f32[(size_t)node * NF + nt * 16 + c] = v;
                }
            }
        }
    }
}

extern "C" void kernel_launch(void* const* d_in, const int* in_sizes, int n_in,
                              void* d_out, int out_size, void* d_ws, size_t ws_size,
                              hipStream_t stream) {
    const int* ei = (const int*)d_in[0];
    const int* row = ei;
    const int* col = ei + N_EDGES;
    const float* emb = (const float*)d_in[1];
    const float* W1_0 = (const float*)d_in[2];
    const float* W1_1 = (const float*)d_in[3];
    const float* b1 = (const float*)d_in[4];
    const float* W2_0 = (const float*)d_in[5];
    const float* W2_1 = (const float*)d_in[6];
    const float* b2 = (const float*)d_in[7];
    float* out = (float*)d_out;

    char* ws = (char*)d_ws;
    int* cnt = (int*)(ws + OFF_CNT);
    int* endp = (int*)(ws + OFF_ENDP);
    float* dinv = (float*)(ws + OFF_DINV);
    int* cur = (int*)(ws + OFF_CUR);
    ushort* pk = (ushort*)(ws + OFF_PKW);
    int* srcs = (int*)(ws + OFF_SRCS);
    ushort* sbinned = (ushort*)(ws + OFF_SBIN);
    int* dbinned = (int*)(ws + OFF_DBIN);
    ushort* emb_bf = (ushort*)(ws + OFF_EMBBF);
    ushort* h_bf = (ushort*)(ws + OFF_HBF);

    hipMemsetAsync(cur, 0, 2 * NBINS * sizeof(int), stream);
    prepsort<<<NBLK + 8 + 3125, 256, 0, stream>>>(W1_0, W1_1, W2_0, W2_1, pk,
                                                  emb, emb_bf, row, col, cur,
                                                  sbinned, dbinned);
    build<<<2 * NBINS, 256, 0, stream>>>(sbinned, dbinned, cur, dinv, cnt, endp, srcs);

    cheb_layer<<<LB2, 128, 0, stream>>>(emb_bf, srcs, dinv, endp, cnt, pk, b1, h_bf, nullptr, 0);
    cheb_layer<<<LB2, 128, 0, stream>>>(h_bf, srcs, dinv, endp, cnt, pk + 8192, b2, nullptr, out, 1);
}

// Round 4
// 188.905 us; speedup vs baseline: 1.1316x; 1.1316x over previous
//
#include <hip/hip_runtime.h>

#define N_NODES 100000
#define N_EDGES 1200000
#define NF 64

typedef __attribute__((ext_vector_type(8))) short short8;
typedef __attribute__((ext_vector_type(4))) float float4v;

__device__ __forceinline__ ushort f2bf(float f) {
    unsigned u = __float_as_uint(f);
    return (ushort)((u + 0x7FFF + ((u >> 16) & 1)) >> 16);  // RNE
}

// binning: bin = node >> 9, 196 bins of 512 nodes (round-2 geometry)
#define NBINS 196
#define CAP 7680                 // max used ~6420 + pads ~800 + 16 tail < 7680
#define EPB 5120                 // edges per sort block (10/thread @512)
#define NBLK 235                 // ceil(1200000/5120)

// ---------------- workspace layout (bytes), flat (~42 MB of 268 MB)
#define OFF_CNT    0             // int[100000]
#define OFF_ENDP   400128        // int[100000]
#define OFF_DINV   800256        // float[100000]
#define OFF_CUR    1200384       // int[2*196] bin-relative cursors (memset 0)
#define OFF_PKW    1202048       // ushort[2*1024*8] = 32 KB packed B-fragments
#define OFF_SRCS   1234816       // int[196*7680]    = 6.02 MB (final, dst-binned)
#define OFF_SBIN   7255936       // ushort[196*7680] = 3.01 MB staging
#define OFF_DBIN   10266496      // int[196*7680]    = 6.02 MB staging
#define OFF_EMBBF  16287616      // ushort[6.4M] = 12.8 MB
#define OFF_HBF    29087616      // ushort[6.4M] = 12.8 MB -> ends 41,887,616

// Fused, 512-thread blocks:
//   blocks [0,235): binsort with LDS local sort -> COALESCED global scatter
//   blocks [235,239): W-pack; blocks [239, 239+1563): emb f32->bf16
// cur[] is BIN-RELATIVE (zeroed by hipMemsetAsync before this launch).
__global__ __launch_bounds__(512) void prepsort(const float* __restrict__ W10,
                                                const float* __restrict__ W11,
                                                const float* __restrict__ W20,
                                                const float* __restrict__ W21,
                                                ushort* __restrict__ pk,
                                                const float* __restrict__ emb,
                                                ushort* __restrict__ emb_bf,
                                                const int* __restrict__ row,
                                                const int* __restrict__ col,
                                                int* __restrict__ cur,
                                                ushort* __restrict__ sbinned,
                                                int* __restrict__ dbinned) {
    int b = blockIdx.x;
    int t = threadIdx.x;
    if (b < NBLK) {
        __shared__ int sh[NBINS], dh[NBINS];        // per-bin counts
        __shared__ int sst[NBINS], dstt[NBINS];     // local exclusive starts
        __shared__ int sgb[NBINS], dgb[NBINS];      // global bases
        __shared__ int slc[NBINS], dlc[NBINS];      // local scatter cursors
        __shared__ int ssc[256], dsc[256];          // scan workspace
        __shared__ ushort sloc[EPB];                // locally sorted src stream
        __shared__ int dloc[EPB];                   // locally sorted dst stream
        __shared__ unsigned char sbid[EPB], dbid[EPB];  // bin id per slot
        for (int i = t; i < NBINS; i += 512) { sh[i] = 0; dh[i] = 0; }
        __syncthreads();
        int base = b * EPB;
        // pass 1: histogram (coalesced reads)
        for (int k = 0; k < EPB / 512; ++k) {
            int e = base + k * 512 + t;
            if (e < N_EDGES) {
                int s = row[e], d = col[e];
                if (s != d) { atomicAdd(&sh[s >> 9], 1); atomicAdd(&dh[d >> 9], 1); }
            }
        }
        __syncthreads();
        // reserve global chunks + local scan
        int cs = 0, cd = 0;
        if (t < NBINS) {
            cs = sh[t]; cd = dh[t];
            sgb[t] = t * CAP + atomicAdd(&cur[t], cs);
            dgb[t] = t * CAP + atomicAdd(&cur[NBINS + t], cd);
        }
        if (t < 256) { ssc[t] = (t < NBINS) ? cs : 0; dsc[t] = (t < NBINS) ? cd : 0; }
        __syncthreads();
        for (int off = 1; off < 256; off <<= 1) {
            int vs = 0, vd = 0;
            if (t < 256 && t >= off) { vs = ssc[t - off]; vd = dsc[t - off]; }
            __syncthreads();
            if (t < 256 && t >= off) { ssc[t] += vs; dsc[t] += vd; }
            __syncthreads();
        }
        if (t < NBINS) {
            sst[t] = ssc[t] - cs; slc[t] = sst[t];
            dstt[t] = dsc[t] - cd; dlc[t] = dstt[t];
        }
        __syncthreads();
        // pass 2: re-read edges (L2-hot), scatter into LDS (cheap random)
        for (int k = 0; k < EPB / 512; ++k) {
            int e = base + k * 512 + t;
            if (e < N_EDGES) {
                int s = row[e], d = col[e];
                if (s != d) {
                    int sb = s >> 9, db = d >> 9;
                    int ls = atomicAdd(&slc[sb], 1);
                    sloc[ls] = (ushort)(s & 511); sbid[ls] = (unsigned char)sb;
                    int ld = atomicAdd(&dlc[db], 1);
                    dloc[ld] = (s << 9) | (d & 511); dbid[ld] = (unsigned char)db;
                }
            }
        }
        __syncthreads();
        // copy-out in slot order: consecutive threads -> consecutive addresses
        int totS = ssc[255], totD = dsc[255];
        for (int i = t; i < totS; i += 512) {
            int bi = sbid[i];
            sbinned[sgb[bi] + (i - sst[bi])] = sloc[i];
        }
        for (int i = t; i < totD; i += 512) {
            int bi = dbid[i];
            dbinned[dgb[bi] + (i - dstt[bi])] = dloc[i];
        }
    } else if (b < NBLK + 4) {
        int idx = (b - NBLK) * 512 + t;   // [0, 2048)
        int layer = idx >> 10;
        int rest = idx & 1023;
        int f = rest >> 6, L = rest & 63;
        int n = (f & 3) * 16 + (L & 15);
        int kb = (f >> 2) * 32 + ((L >> 4) << 3);
#pragma unroll
        for (int j = 0; j < 8; ++j) {
            int k = kb + j;
            const float* W = layer ? ((k < 64) ? W20 : W21) : ((k < 64) ? W10 : W11);
            pk[idx * 8 + j] = f2bf(W[(k & 63) * 64 + n]);
        }
    } else {
        int bb = b - NBLK - 4;            // [0, 1563)
        int i = (bb * 512 + t) * 8;
        if (i < N_NODES * NF) {
            float4 v0 = *(const float4*)(emb + i);
            float4 v1 = *(const float4*)(emb + i + 4);
            uint4 o;
            o.x = (uint)f2bf(v0.x) | ((uint)f2bf(v0.y) << 16);
            o.y = (uint)f2bf(v0.z) | ((uint)f2bf(v0.w) << 16);
            o.z = (uint)f2bf(v1.x) | ((uint)f2bf(v1.y) << 16);
            o.w = (uint)f2bf(v1.z) | ((uint)f2bf(v1.w) << 16);
            *(uint4*)(emb_bf + i) = o;
        }
    }
}

// blocks [0,196): per src-bin hist -> dinv
// blocks [196,392): per dst-bin hist+scan -> LDS obuf scatter -> COALESCED srcs write
__global__ __launch_bounds__(512) void build(const ushort* __restrict__ sbinned,
                                             const int* __restrict__ dbinned,
                                             const int* __restrict__ cur,
                                             float* __restrict__ dinv,
                                             int* __restrict__ cnt,
                                             int* __restrict__ endp,
                                             int* __restrict__ srcs) {
    int t = threadIdx.x;
    int b = blockIdx.x;
    if (b < NBINS) {
        __shared__ int hist[512];
        hist[t] = 0;
        __syncthreads();
        int start = b * CAP;
        int len = cur[b];
        for (int i = t; i < len; i += 512)
            atomicAdd(&hist[sbinned[start + i]], 1);
        __syncthreads();
        int n0 = (b << 9) + t;
        if (n0 < N_NODES) dinv[n0] = hist[t] ? rsqrtf((float)hist[t]) : 0.0f;
    } else {
        int bb = b - NBINS;
        __shared__ int hist[512];
        __shared__ int lcur[512];
        __shared__ int obuf[CAP];             // 30 KB local out-buffer
        __shared__ int tot_s;
        hist[t] = 0;
        __syncthreads();
        int start = bb * CAP;
        int len = cur[NBINS + bb];
        // pass 1: hist (coalesced reads)
        for (int i = t; i < len; i += 512)
            atomicAdd(&hist[dbinned[start + i] & 511], 1);
        __syncthreads();
        int o0 = hist[t];
        int A0 = (o0 + 3) & ~3;
        __syncthreads();
        hist[t] = A0;
        __syncthreads();
        for (int off = 1; off < 512; off <<= 1) {
            int v = (t >= off) ? hist[t - off] : 0;
            __syncthreads();
            hist[t] += v;
            __syncthreads();
        }
        int e0 = hist[t] - A0;   // local exclusive (aligned)
        if (t == 511) tot_s = hist[511];
        lcur[t] = e0;
        int n0 = (bb << 9) + t;
        if (n0 < N_NODES) { cnt[n0] = o0; endp[n0] = start + e0 + o0; }
        __syncthreads();
        // pass 2: re-read (L2-hot), scatter into LDS obuf
        for (int i = t; i < len; i += 512) {
            int p = dbinned[start + i];
            int slot = atomicAdd(&lcur[p & 511], 1);
            obuf[slot] = p >> 9;
        }
        // zero per-node alignment pads + 16-slot bin tail, in LDS
        for (int k = o0; k < A0; ++k) obuf[e0 + k] = 0;
        __syncthreads();
        if (t < 16) obuf[tot_s + t] = 0;
        __syncthreads();
        // coalesced copy-out of the whole bin
        int tot = tot_s + 16;
        for (int i = t; i < tot; i += 512) srcs[start + i] = obuf[i];
    }
}

// Fused layer (UNCHANGED, verified): 16 nodes/wave; 4 edges/gather-instr;
// pair-interleaved chunks; dinv[src] on the fly; -dinv[dst] applied once/node.
#define NPW 16
#define WPB 2
#define NPB (NPW * WPB)                       // 32
#define LB2 ((N_NODES + NPB - 1) / NPB)       // 3125

__global__ __launch_bounds__(128, 8) void cheb_layer(const ushort* __restrict__ x,
                                                     const int* __restrict__ srcs,
                                                     const float* __restrict__ dinv,
                                                     const int* __restrict__ endp,
                                                     const int* __restrict__ cnt,
                                                     const ushort* __restrict__ pk,
                                                     const float* __restrict__ bias,
                                                     ushort* __restrict__ out_bf,
                                                     float* __restrict__ out_f32,
                                                     int last) {
    __shared__ ushort sA[WPB][16][136];   // 8.7 KB

    int t = threadIdx.x;
    int lane = t & 63, wid = t >> 6;
    int c = lane & 15, q = lane >> 4;
    int qd = q, fg = c;
    int nb = blockIdx.x * NPB + wid * NPW;

    int nend = 0, ncnt = 0;
    if (lane < NPW && nb + lane < N_NODES) {
        nend = endp[nb + lane];
        ncnt = cnt[nb + lane];
    }

    const uint2* xr = (const uint2*)x;   // row = 16 uint2 (64 bf16)

    auto chunk8 = [&](int eb, int eendL, float& a0, float& a1, float& a2, float& a3) {
        int4 sv = *(const int4*)(srcs + eb);       // edges eb..eb+3 (uniform)
        int4 sw = *(const int4*)(srcs + eb + 4);   // edges eb+4..eb+7
        int sA01 = (qd & 1) ? sv.y : sv.x;
        int sA23 = (qd & 1) ? sv.w : sv.z;
        int srcA = (qd & 2) ? sA23 : sA01;
        int sB01 = (qd & 1) ? sw.y : sw.x;
        int sB23 = (qd & 1) ? sw.w : sw.z;
        int srcB = (qd & 2) ? sB23 : sB01;
        float nAf = dinv[srcA];                    // broadcast within quarter
        float nBf = dinv[srcB];
        nAf = (eb + qd < eendL) ? nAf : 0.0f;
        nBf = (eb + 4 + qd < eendL) ? nBf : 0.0f;
        uint2 gA = xr[(size_t)srcA * 16 + fg];
        uint2 gB = xr[(size_t)srcB * 16 + fg];
        a0 = fmaf(nAf, __uint_as_float(gA.x << 16), a0);
        a1 = fmaf(nAf, __uint_as_float(gA.x & 0xffff0000u), a1);
        a2 = fmaf(nAf, __uint_as_float(gA.y << 16), a2);
        a3 = fmaf(nAf, __uint_as_float(gA.y & 0xffff0000u), a3);
        a0 = fmaf(nBf, __uint_as_float(gB.x << 16), a0);
        a1 = fmaf(nBf, __uint_as_float(gB.x & 0xffff0000u), a1);
        a2 = fmaf(nBf, __uint_as_float(gB.y << 16), a2);
        a3 = fmaf(nBf, __uint_as_float(gB.y & 0xffff0000u), a3);
    };

#pragma unroll
    for (int gp = 0; gp < NPW; gp += 2) {
        int cn0 = __builtin_amdgcn_readlane(ncnt, gp);
        int ee0 = __builtin_amdgcn_readlane(nend, gp);
        int cn1 = __builtin_amdgcn_readlane(ncnt, gp + 1);
        int ee1 = __builtin_amdgcn_readlane(nend, gp + 1);
        int s0 = ee0 - cn0, s1 = ee1 - cn1;   // 4-aligned starts
        float a0 = 0, a1 = 0, a2 = 0, a3 = 0;
        float b0 = 0, b1 = 0, b2 = 0, b3 = 0;

        // static 2x8-edge chunks per node, pair-interleaved (masked; safe via tail)
        chunk8(s0,     ee0, a0, a1, a2, a3);
        chunk8(s1,     ee1, b0, b1, b2, b3);
        chunk8(s0 + 8, ee0, a0, a1, a2, a3);
        chunk8(s1 + 8, ee1, b0, b1, b2, b3);
        // rare heavy nodes (cn > 16)
        for (int e = s0 + 16; e < ee0; e += 8) chunk8(e, ee0, a0, a1, a2, a3);
        for (int e = s1 + 16; e < ee1; e += 8) chunk8(e, ee1, b0, b1, b2, b3);

        // interleaved cross-quarter reductions for both nodes
        a0 += __shfl_xor(a0, 16, 64); b0 += __shfl_xor(b0, 16, 64);
        a1 += __shfl_xor(a1, 16, 64); b1 += __shfl_xor(b1, 16, 64);
        a2 += __shfl_xor(a2, 16, 64); b2 += __shfl_xor(b2, 16, 64);
        a3 += __shfl_xor(a3, 16, 64); b3 += __shfl_xor(b3, 16, 64);
        a0 += __shfl_xor(a0, 32, 64); b0 += __shfl_xor(b0, 32, 64);
        a1 += __shfl_xor(a1, 32, 64); b1 += __shfl_xor(b1, 32, 64);
        a2 += __shfl_xor(a2, 32, 64); b2 += __shfl_xor(b2, 32, 64);
        a3 += __shfl_xor(a3, 32, 64); b3 += __shfl_xor(b3, 32, 64);

        int node0 = nb + gp, node1 = nb + gp + 1;
        int ni0 = (node0 < N_NODES) ? node0 : 0;
        int ni1 = (node1 < N_NODES) ? node1 : 0;
        if (qd == 0) {
            uint2 xv0 = xr[(size_t)ni0 * 16 + fg];
            uint2 xv1 = xr[(size_t)ni1 * 16 + fg];
            *(uint2*)&sA[wid][gp][4 * fg] = xv0;
            *(uint2*)&sA[wid][gp + 1][4 * fg] = xv1;
        }
        if (qd == 1) {
            float sc0 = -dinv[ni0];   // apply dst-side norm once per node
            float sc1 = -dinv[ni1];
            uint2 p0, p1;
            p0.x = (uint)f2bf(a0 * sc0) | ((uint)f2bf(a1 * sc0) << 16);
            p0.y = (uint)f2bf(a2 * sc0) | ((uint)f2bf(a3 * sc0) << 16);
            p1.x = (uint)f2bf(b0 * sc1) | ((uint)f2bf(b1 * sc1) << 16);
            p1.y = (uint)f2bf(b2 * sc1) | ((uint)f2bf(b3 * sc1) << 16);
            *(uint2*)&sA[wid][gp][64 + 4 * fg] = p0;
            *(uint2*)&sA[wid][gp + 1][64 + 4 * fg] = p1;
        }
    }
    __builtin_amdgcn_wave_barrier();

    const short8* pk8 = (const short8*)pk;
    float4v C[4];
#pragma unroll
    for (int nt = 0; nt < 4; ++nt) {
        float b = bias[nt * 16 + c];
        C[nt] = (float4v){b, b, b, b};
    }
#pragma unroll
    for (int kt = 0; kt < 4; ++kt) {
        short8 af = *(const short8*)&sA[wid][c][kt * 32 + q * 8];
#pragma unroll
        for (int nt = 0; nt < 4; ++nt) {
            short8 bfr = pk8[(kt * 4 + nt) * 64 + lane];
            C[nt] = __builtin_amdgcn_mfma_f32_16x16x32_bf16(af, bfr, C[nt], 0, 0, 0);
        }
    }

#pragma unroll
    for (int nt = 0; nt < 4; ++nt) {
#pragma unroll
        for (int i = 0; i < 4; ++i) {
            int node = nb + q * 4 + i;
            if (node < N_NODES) {
                float v = C[nt][i];
                if (!last) {
                    v = fmaxf(v, 0.0f);
                    out_bf[(size_t)node * NF + nt * 16 + c] = f2bf(v);
                } else {
                    out_f32[(size_t)node * NF + nt * 16 + c] = v;
                }
            }
        }
    }
}

extern "C" void kernel_launch(void* const* d_in, const int* in_sizes, int n_in,
                              void* d_out, int out_size, void* d_ws, size_t ws_size,
                              hipStream_t stream) {
    const int* ei = (const int*)d_in[0];
    const int* row = ei;
    const int* col = ei + N_EDGES;
    const float* emb = (const float*)d_in[1];
    const float* W1_0 = (const float*)d_in[2];
    const float* W1_1 = (const float*)d_in[3];
    const float* b1 = (const float*)d_in[4];
    const float* W2_0 = (const float*)d_in[5];
    const float* W2_1 = (const float*)d_in[6];
    const float* b2 = (const float*)d_in[7];
    float* out = (float*)d_out;

    char* ws = (char*)d_ws;
    int* cnt = (int*)(ws + OFF_CNT);
    int* endp = (int*)(ws + OFF_ENDP);
    float* dinv = (float*)(ws + OFF_DINV);
    int* cur = (int*)(ws + OFF_CUR);
    ushort* pk = (ushort*)(ws + OFF_PKW);
    int* srcs = (int*)(ws + OFF_SRCS);
    ushort* sbinned = (ushort*)(ws + OFF_SBIN);
    int* dbinned = (int*)(ws + OFF_DBIN);
    ushort* emb_bf = (ushort*)(ws + OFF_EMBBF);
    ushort* h_bf = (ushort*)(ws + OFF_HBF);

    hipMemsetAsync(cur, 0, 2 * NBINS * sizeof(int), stream);
    prepsort<<<NBLK + 4 + 1563, 512, 0, stream>>>(W1_0, W1_1, W2_0, W2_1, pk,
                                                  emb, emb_bf, row, col, cur,
                                                  sbinned, dbinned);
    build<<<2 * NBINS, 512, 0, stream>>>(sbinned, dbinned, cur, dinv, cnt, endp, srcs);

    cheb_layer<<<LB2, 128, 0, stream>>>(emb_bf, srcs, dinv, endp, cnt, pk, b1, h_bf, nullptr, 0);
    cheb_layer<<<LB2, 128, 0, stream>>>(h_bf, srcs, dinv, endp, cnt, pk + 8192, b2, nullptr, out, 1);
}

// Round 5
// 187.210 us; speedup vs baseline: 1.1418x; 1.0091x over previous
//
#include <hip/hip_runtime.h>

#define N_NODES 100000
#define N_EDGES 1200000
#define NF 64

typedef __attribute__((ext_vector_type(8))) short short8;
typedef __attribute__((ext_vector_type(4))) float float4v;

__device__ __forceinline__ ushort f2bf(float f) {
    unsigned u = __float_as_uint(f);
    return (ushort)((u + 0x7FFF + ((u >> 16) & 1)) >> 16);  // RNE
}

// binning: bin = node >> 8, 391 bins of 256 nodes.
// LDS-bounce keeps global scatters coalesced independent of bin size (r4 lesson).
#define NBINS 391
#define CAP 4352                 // in-edges ~3253 max + pads <=768 + 16 tail << 4352
#define EPB 4096                 // edges per sort block (8/thread @512, in registers)
#define NBLK 293                 // ceil(1200000/4096)
#define NI4 (N_EDGES / 4)        // 300000 int4s per row/col array

// ---------------- workspace layout (bytes), flat (~44 MB of 268 MB)
#define OFF_CNT    0             // int[100000]
#define OFF_ENDP   400128        // int[100000]
#define OFF_DINV   800256        // float[100000]
#define OFF_CUR    1200384       // int[2*391] bin-relative cursors (memset 0)
#define OFF_PKW    1203584       // ushort[2*1024*8] = 32 KB packed B-fragments
#define OFF_SRCS   1236352       // int[391*4352]    = 6.8 MB (final, dst-binned)
#define OFF_SBIN   8042880       // ushort[391*4352] = 3.4 MB staging
#define OFF_DBIN   11446144      // int[391*4352]    = 6.8 MB staging
#define OFF_EMBBF  18252672      // ushort[6.4M] = 12.8 MB
#define OFF_HBF    31052672      // ushort[6.4M] = 12.8 MB -> ends 43,852,672

// Fused, 512-thread blocks:
//   blocks [0,293): binsort, SINGLE edge read (regs) -> LDS local sort ->
//                   coalesced global scatter
//   blocks [293,297): W-pack; blocks [297, 297+1563): emb f32->bf16
// cur[] is BIN-RELATIVE (zeroed by hipMemsetAsync before this launch).
__global__ __launch_bounds__(512) void prepsort(const float* __restrict__ W10,
                                                const float* __restrict__ W11,
                                                const float* __restrict__ W20,
                                                const float* __restrict__ W21,
                                                ushort* __restrict__ pk,
                                                const float* __restrict__ emb,
                                                ushort* __restrict__ emb_bf,
                                                const int* __restrict__ row,
                                                const int* __restrict__ col,
                                                int* __restrict__ cur,
                                                ushort* __restrict__ sbinned,
                                                int* __restrict__ dbinned) {
    int b = blockIdx.x;
    int t = threadIdx.x;
    if (b < NBLK) {
        __shared__ int sh[NBINS], dh[NBINS];        // per-bin counts
        __shared__ int sst[NBINS], dstt[NBINS];     // local exclusive starts
        __shared__ int sgb[NBINS], dgb[NBINS];      // global bases
        __shared__ int slc[NBINS], dlc[NBINS];      // local scatter cursors
        __shared__ int ssc[512], dsc[512];          // scan workspace
        __shared__ ushort sloc[EPB];                // locally sorted src stream
        __shared__ int dloc[EPB];                   // locally sorted dst stream
        __shared__ ushort sbid[EPB], dbid[EPB];     // bin id per slot (391>255)
        for (int i = t; i < NBINS; i += 512) { sh[i] = 0; dh[i] = 0; }
        __syncthreads();
        // single edge read: 8 edges/thread held in registers
        int i40 = b * (EPB / 4) + t * 2;
        int4 r0 = make_int4(-1, -1, -1, -1), c0 = r0, r1 = r0, c1 = r0;
        if (i40 < NI4)     { r0 = ((const int4*)row)[i40];     c0 = ((const int4*)col)[i40]; }
        if (i40 + 1 < NI4) { r1 = ((const int4*)row)[i40 + 1]; c1 = ((const int4*)col)[i40 + 1]; }
        int s_[8] = {r0.x, r0.y, r0.z, r0.w, r1.x, r1.y, r1.z, r1.w};
        int d_[8] = {c0.x, c0.y, c0.z, c0.w, c1.x, c1.y, c1.z, c1.w};
#pragma unroll
        for (int j = 0; j < 8; ++j)
            if (s_[j] >= 0 && s_[j] != d_[j]) {
                atomicAdd(&sh[s_[j] >> 8], 1);
                atomicAdd(&dh[d_[j] >> 8], 1);
            }
        __syncthreads();
        // reserve global chunks + local scan (512-wide, zero-padded)
        int cs = 0, cd = 0;
        if (t < NBINS) {
            cs = sh[t]; cd = dh[t];
            sgb[t] = t * CAP + atomicAdd(&cur[t], cs);
            dgb[t] = t * CAP + atomicAdd(&cur[NBINS + t], cd);
        }
        ssc[t] = (t < NBINS) ? cs : 0;
        dsc[t] = (t < NBINS) ? cd : 0;
        __syncthreads();
        for (int off = 1; off < 512; off <<= 1) {
            int vs = 0, vd = 0;
            if (t >= off) { vs = ssc[t - off]; vd = dsc[t - off]; }
            __syncthreads();
            ssc[t] += vs; dsc[t] += vd;
            __syncthreads();
        }
        if (t < NBINS) {
            sst[t] = ssc[t] - cs; slc[t] = sst[t];
            dstt[t] = dsc[t] - cd; dlc[t] = dstt[t];
        }
        __syncthreads();
        // scatter from registers into LDS (cheap random)
#pragma unroll
        for (int j = 0; j < 8; ++j) {
            int s = s_[j], d = d_[j];
            if (s >= 0 && s != d) {
                int sb = s >> 8, db = d >> 8;
                int ls = atomicAdd(&slc[sb], 1);
                sloc[ls] = (ushort)(s & 255); sbid[ls] = (ushort)sb;
                int ld = atomicAdd(&dlc[db], 1);
                dloc[ld] = (s << 8) | (d & 255); dbid[ld] = (ushort)db;
            }
        }
        __syncthreads();
        // copy-out in slot order: consecutive threads -> consecutive addresses
        int totS = ssc[511], totD = dsc[511];
        for (int i = t; i < totS; i += 512) {
            int bi = sbid[i];
            sbinned[sgb[bi] + (i - sst[bi])] = sloc[i];
        }
        for (int i = t; i < totD; i += 512) {
            int bi = dbid[i];
            dbinned[dgb[bi] + (i - dstt[bi])] = dloc[i];
        }
    } else if (b < NBLK + 4) {
        int idx = (b - NBLK) * 512 + t;   // [0, 2048)
        int layer = idx >> 10;
        int rest = idx & 1023;
        int f = rest >> 6, L = rest & 63;
        int n = (f & 3) * 16 + (L & 15);
        int kb = (f >> 2) * 32 + ((L >> 4) << 3);
#pragma unroll
        for (int j = 0; j < 8; ++j) {
            int k = kb + j;
            const float* W = layer ? ((k < 64) ? W20 : W21) : ((k < 64) ? W10 : W11);
            pk[idx * 8 + j] = f2bf(W[(k & 63) * 64 + n]);
        }
    } else {
        int bb = b - NBLK - 4;            // [0, 1563)
        int i = (bb * 512 + t) * 8;
        if (i < N_NODES * NF) {
            float4 v0 = *(const float4*)(emb + i);
            float4 v1 = *(const float4*)(emb + i + 4);
            uint4 o;
            o.x = (uint)f2bf(v0.x) | ((uint)f2bf(v0.y) << 16);
            o.y = (uint)f2bf(v0.z) | ((uint)f2bf(v0.w) << 16);
            o.z = (uint)f2bf(v1.x) | ((uint)f2bf(v1.y) << 16);
            o.w = (uint)f2bf(v1.z) | ((uint)f2bf(v1.w) << 16);
            *(uint4*)(emb_bf + i) = o;
        }
    }
}

// 256-thread blocks, 782 total (~3/CU):
// blocks [0,391): per src-bin hist -> dinv
// blocks [391,782): per dst-bin hist+scan -> LDS obuf scatter -> coalesced srcs
__global__ __launch_bounds__(256) void build(const ushort* __restrict__ sbinned,
                                             const int* __restrict__ dbinned,
                                             const int* __restrict__ cur,
                                             float* __restrict__ dinv,
                                             int* __restrict__ cnt,
                                             int* __restrict__ endp,
                                             int* __restrict__ srcs) {
    int t = threadIdx.x;
    int b = blockIdx.x;
    if (b < NBINS) {
        __shared__ int hist[256];
        hist[t] = 0;
        __syncthreads();
        int start = b * CAP;
        int len = cur[b];
        for (int i = t; i < len; i += 256)
            atomicAdd(&hist[sbinned[start + i]], 1);
        __syncthreads();
        int n0 = (b << 8) + t;
        if (n0 < N_NODES) dinv[n0] = hist[t] ? rsqrtf((float)hist[t]) : 0.0f;
    } else {
        int bb = b - NBINS;
        __shared__ int hist[256];
        __shared__ int lcur[256];
        __shared__ int obuf[CAP];             // 17.4 KB local out-buffer
        __shared__ int tot_s;
        hist[t] = 0;
        __syncthreads();
        int start = bb * CAP;
        int len = cur[NBINS + bb];
        // pass 1: hist (coalesced reads)
        for (int i = t; i < len; i += 256)
            atomicAdd(&hist[dbinned[start + i] & 255], 1);
        __syncthreads();
        int o0 = hist[t];
        int A0 = (o0 + 3) & ~3;
        __syncthreads();
        hist[t] = A0;
        __syncthreads();
        for (int off = 1; off < 256; off <<= 1) {
            int v = (t >= off) ? hist[t - off] : 0;
            __syncthreads();
            hist[t] += v;
            __syncthreads();
        }
        int e0 = hist[t] - A0;   // local exclusive (aligned)
        if (t == 255) tot_s = hist[255];
        lcur[t] = e0;
        int n0 = (bb << 8) + t;
        if (n0 < N_NODES) { cnt[n0] = o0; endp[n0] = start + e0 + o0; }
        __syncthreads();
        // pass 2: re-read (L2-hot), scatter into LDS obuf
        for (int i = t; i < len; i += 256) {
            int p = dbinned[start + i];
            int slot = atomicAdd(&lcur[p & 255], 1);
            obuf[slot] = p >> 8;
        }
        // zero per-node alignment pads + 16-slot bin tail, in LDS
        for (int k = o0; k < A0; ++k) obuf[e0 + k] = 0;
        __syncthreads();
        if (t < 16) obuf[tot_s + t] = 0;
        __syncthreads();
        // coalesced copy-out of the whole bin
        int tot = tot_s + 16;
        for (int i = t; i < tot; i += 256) srcs[start + i] = obuf[i];
    }
}

// Fused layer (UNCHANGED, verified): 16 nodes/wave; 4 edges/gather-instr;
// pair-interleaved chunks; dinv[src] on the fly; -dinv[dst] applied once/node.
#define NPW 16
#define WPB 2
#define NPB (NPW * WPB)                       // 32
#define LB2 ((N_NODES + NPB - 1) / NPB)       // 3125

__global__ __launch_bounds__(128, 8) void cheb_layer(const ushort* __restrict__ x,
                                                     const int* __restrict__ srcs,
                                                     const float* __restrict__ dinv,
                                                     const int* __restrict__ endp,
                                                     const int* __restrict__ cnt,
                                                     const ushort* __restrict__ pk,
                                                     const float* __restrict__ bias,
                                                     ushort* __restrict__ out_bf,
                                                     float* __restrict__ out_f32,
                                                     int last) {
    __shared__ ushort sA[WPB][16][136];   // 8.7 KB

    int t = threadIdx.x;
    int lane = t & 63, wid = t >> 6;
    int c = lane & 15, q = lane >> 4;
    int qd = q, fg = c;
    int nb = blockIdx.x * NPB + wid * NPW;

    int nend = 0, ncnt = 0;
    if (lane < NPW && nb + lane < N_NODES) {
        nend = endp[nb + lane];
        ncnt = cnt[nb + lane];
    }

    const uint2* xr = (const uint2*)x;   // row = 16 uint2 (64 bf16)

    auto chunk8 = [&](int eb, int eendL, float& a0, float& a1, float& a2, float& a3) {
        int4 sv = *(const int4*)(srcs + eb);       // edges eb..eb+3 (uniform)
        int4 sw = *(const int4*)(srcs + eb + 4);   // edges eb+4..eb+7
        int sA01 = (qd & 1) ? sv.y : sv.x;
        int sA23 = (qd & 1) ? sv.w : sv.z;
        int srcA = (qd & 2) ? sA23 : sA01;
        int sB01 = (qd & 1) ? sw.y : sw.x;
        int sB23 = (qd & 1) ? sw.w : sw.z;
        int srcB = (qd & 2) ? sB23 : sB01;
        float nAf = dinv[srcA];                    // broadcast within quarter
        float nBf = dinv[srcB];
        nAf = (eb + qd < eendL) ? nAf : 0.0f;
        nBf = (eb + 4 + qd < eendL) ? nBf : 0.0f;
        uint2 gA = xr[(size_t)srcA * 16 + fg];
        uint2 gB = xr[(size_t)srcB * 16 + fg];
        a0 = fmaf(nAf, __uint_as_float(gA.x << 16), a0);
        a1 = fmaf(nAf, __uint_as_float(gA.x & 0xffff0000u), a1);
        a2 = fmaf(nAf, __uint_as_float(gA.y << 16), a2);
        a3 = fmaf(nAf, __uint_as_float(gA.y & 0xffff0000u), a3);
        a0 = fmaf(nBf, __uint_as_float(gB.x << 16), a0);
        a1 = fmaf(nBf, __uint_as_float(gB.x & 0xffff0000u), a1);
        a2 = fmaf(nBf, __uint_as_float(gB.y << 16), a2);
        a3 = fmaf(nBf, __uint_as_float(gB.y & 0xffff0000u), a3);
    };

#pragma unroll
    for (int gp = 0; gp < NPW; gp += 2) {
        int cn0 = __builtin_amdgcn_readlane(ncnt, gp);
        int ee0 = __builtin_amdgcn_readlane(nend, gp);
        int cn1 = __builtin_amdgcn_readlane(ncnt, gp + 1);
        int ee1 = __builtin_amdgcn_readlane(nend, gp + 1);
        int s0 = ee0 - cn0, s1 = ee1 - cn1;   // 4-aligned starts
        float a0 = 0, a1 = 0, a2 = 0, a3 = 0;
        float b0 = 0, b1 = 0, b2 = 0, b3 = 0;

        // static 2x8-edge chunks per node, pair-interleaved (masked; safe via tail)
        chunk8(s0,     ee0, a0, a1, a2, a3);
        chunk8(s1,     ee1, b0, b1, b2, b3);
        chunk8(s0 + 8, ee0, a0, a1, a2, a3);
        chunk8(s1 + 8, ee1, b0, b1, b2, b3);
        // rare heavy nodes (cn > 16)
        for (int e = s0 + 16; e < ee0; e += 8) chunk8(e, ee0, a0, a1, a2, a3);
        for (int e = s1 + 16; e < ee1; e += 8) chunk8(e, ee1, b0, b1, b2, b3);

        // interleaved cross-quarter reductions for both nodes
        a0 += __shfl_xor(a0, 16, 64); b0 += __shfl_xor(b0, 16, 64);
        a1 += __shfl_xor(a1, 16, 64); b1 += __shfl_xor(b1, 16, 64);
        a2 += __shfl_xor(a2, 16, 64); b2 += __shfl_xor(b2, 16, 64);
        a3 += __shfl_xor(a3, 16, 64); b3 += __shfl_xor(b3, 16, 64);
        a0 += __shfl_xor(a0, 32, 64); b0 += __shfl_xor(b0, 32, 64);
        a1 += __shfl_xor(a1, 32, 64); b1 += __shfl_xor(b1, 32, 64);
        a2 += __shfl_xor(a2, 32, 64); b2 += __shfl_xor(b2, 32, 64);
        a3 += __shfl_xor(a3, 32, 64); b3 += __shfl_xor(b3, 32, 64);

        int node0 = nb + gp, node1 = nb + gp + 1;
        int ni0 = (node0 < N_NODES) ? node0 : 0;
        int ni1 = (node1 < N_NODES) ? node1 : 0;
        if (qd == 0) {
            uint2 xv0 = xr[(size_t)ni0 * 16 + fg];
            uint2 xv1 = xr[(size_t)ni1 * 16 + fg];
            *(uint2*)&sA[wid][gp][4 * fg] = xv0;
            *(uint2*)&sA[wid][gp + 1][4 * fg] = xv1;
        }
        if (qd == 1) {
            float sc0 = -dinv[ni0];   // apply dst-side norm once per node
            float sc1 = -dinv[ni1];
            uint2 p0, p1;
            p0.x = (uint)f2bf(a0 * sc0) | ((uint)f2bf(a1 * sc0) << 16);
            p0.y = (uint)f2bf(a2 * sc0) | ((uint)f2bf(a3 * sc0) << 16);
            p1.x = (uint)f2bf(b0 * sc1) | ((uint)f2bf(b1 * sc1) << 16);
            p1.y = (uint)f2bf(b2 * sc1) | ((uint)f2bf(b3 * sc1) << 16);
            *(uint2*)&sA[wid][gp][64 + 4 * fg] = p0;
            *(uint2*)&sA[wid][gp + 1][64 + 4 * fg] = p1;
        }
    }
    __builtin_amdgcn_wave_barrier();

    const short8* pk8 = (const short8*)pk;
    float4v C[4];
#pragma unroll
    for (int nt = 0; nt < 4; ++nt) {
        float b = bias[nt * 16 + c];
        C[nt] = (float4v){b, b, b, b};
    }
#pragma unroll
    for (int kt = 0; kt < 4; ++kt) {
        short8 af = *(const short8*)&sA[wid][c][kt * 32 + q * 8];
#pragma unroll
        for (int nt = 0; nt < 4; ++nt) {
            short8 bfr = pk8[(kt * 4 + nt) * 64 + lane];
            C[nt] = __builtin_amdgcn_mfma_f32_16x16x32_bf16(af, bfr, C[nt], 0, 0, 0);
        }
    }

#pragma unroll
    for (int nt = 0; nt < 4; ++nt) {
#pragma unroll
        for (int i = 0; i < 4; ++i) {
            int node = nb + q * 4 + i;
            if (node < N_NODES) {
                float v = C[nt][i];
                if (!last) {
                    v = fmaxf(v, 0.0f);
                    out_bf[(size_t)node * NF + nt * 16 + c] = f2bf(v);
                } else {
                    out_f32[(size_t)node * NF + nt * 16 + c] = v;
                }
            }
        }
    }
}

extern "C" void kernel_launch(void* const* d_in, const int* in_sizes, int n_in,
                              void* d_out, int out_size, void* d_ws, size_t ws_size,
                              hipStream_t stream) {
    const int* ei = (const int*)d_in[0];
    const int* row = ei;
    const int* col = ei + N_EDGES;
    const float* emb = (const float*)d_in[1];
    const float* W1_0 = (const float*)d_in[2];
    const float* W1_1 = (const float*)d_in[3];
    const float* b1 = (const float*)d_in[4];
    const float* W2_0 = (const float*)d_in[5];
    const float* W2_1 = (const float*)d_in[6];
    const float* b2 = (const float*)d_in[7];
    float* out = (float*)d_out;

    char* ws = (char*)d_ws;
    int* cnt = (int*)(ws + OFF_CNT);
    int* endp = (int*)(ws + OFF_ENDP);
    float* dinv = (float*)(ws + OFF_DINV);
    int* cur = (int*)(ws + OFF_CUR);
    ushort* pk = (ushort*)(ws + OFF_PKW);
    int* srcs = (int*)(ws + OFF_SRCS);
    ushort* sbinned = (ushort*)(ws + OFF_SBIN);
    int* dbinned = (int*)(ws + OFF_DBIN);
    ushort* emb_bf = (ushort*)(ws + OFF_EMBBF);
    ushort* h_bf = (ushort*)(ws + OFF_HBF);

    hipMemsetAsync(cur, 0, 2 * NBINS * sizeof(int), stream);
    prepsort<<<NBLK + 4 + 1563, 512, 0, stream>>>(W1_0, W1_1, W2_0, W2_1, pk,
                                                  emb, emb_bf, row, col, cur,
                                                  sbinned, dbinned);
    build<<<2 * NBINS, 256, 0, stream>>>(sbinned, dbinned, cur, dinv, cnt, endp, srcs);

    cheb_layer<<<LB2, 128, 0, stream>>>(emb_bf, srcs, dinv, endp, cnt, pk, b1, h_bf, nullptr, 0);
    cheb_layer<<<LB2, 128, 0, stream>>>(h_bf, srcs, dinv, endp, cnt, pk + 8192, b2, nullptr, out, 1);
}